// Round 1
// baseline (5398.005 us; speedup 1.0000x reference)
//
#include <hip/hip_runtime.h>
#include <hip/hip_bf16.h>
#include <math.h>

#define N_EMBD 1024
#define N_HEAD 16
#define HS 64          // head size = wavefront size
#define BT 4096        // B*T rows
#define TSEQ 2048

// ---------------- Tiled fp32 GEMM with bias: C[M,N] = A[M,K] @ W[K,N] + bias[N]
#define TILE 64
#define BKK 32
__global__ __launch_bounds__(256) void gemm_bias_f32(
    const float* __restrict__ A, const float* __restrict__ W,
    const float* __restrict__ bias, float* __restrict__ C,
    int M, int N, int K) {
  __shared__ float As[BKK][TILE + 1];
  __shared__ float Bs[BKK][TILE + 1];
  const int bm = blockIdx.y * TILE;
  const int bn = blockIdx.x * TILE;
  const int tid = threadIdx.x;
  const int tn = tid & 15;   // 16 col groups
  const int tm = tid >> 4;   // 16 row groups
  float acc[4][4] = {};
  for (int k0 = 0; k0 < K; k0 += BKK) {
    // load A tile (64 rows x 32 k), store transposed As[k][m]
#pragma unroll
    for (int i = 0; i < 8; ++i) {
      int idx = tid + i * 256;        // 0..2047
      int m  = idx >> 5;              // /32
      int kk = idx & 31;
      As[kk][m] = A[(size_t)(bm + m) * K + k0 + kk];
    }
    // load B tile (32 k x 64 n)
#pragma unroll
    for (int i = 0; i < 8; ++i) {
      int idx = tid + i * 256;
      int kk = idx >> 6;              // /64
      int n  = idx & 63;
      Bs[kk][n] = W[(size_t)(k0 + kk) * N + bn + n];
    }
    __syncthreads();
#pragma unroll
    for (int kk = 0; kk < BKK; ++kk) {
      float a[4], b[4];
#pragma unroll
      for (int i = 0; i < 4; ++i) a[i] = As[kk][tm * 4 + i];
#pragma unroll
      for (int j = 0; j < 4; ++j) b[j] = Bs[kk][tn * 4 + j];
#pragma unroll
      for (int i = 0; i < 4; ++i)
#pragma unroll
        for (int j = 0; j < 4; ++j) acc[i][j] += a[i] * b[j];
    }
    __syncthreads();
  }
#pragma unroll
  for (int i = 0; i < 4; ++i)
#pragma unroll
    for (int j = 0; j < 4; ++j) {
      int m = bm + tm * 4 + i, n = bn + tn * 4 + j;
      C[(size_t)m * N + n] = acc[i][j] + bias[n];
    }
}

// ---------------- Flash-style causal attention, fp32
// One wave per (b, h, q): lane = head dim. Online softmax over k=0..q.
// qkv layout: [B*T, 3C]; q at col h*64, k at C + h*64, v at 2C + h*64.
__global__ __launch_bounds__(256) void attn_causal_f32(
    const float* __restrict__ qkv, float* __restrict__ Y) {
  const int lane = threadIdx.x & 63;
  const int widx = threadIdx.x >> 6;               // wave in block (0..3)
  const int wave_id = blockIdx.x * 4 + widx;       // 0..65535
  const int q  = wave_id & (TSEQ - 1);
  const int h  = (wave_id / TSEQ) & (N_HEAD - 1);
  const int b  = wave_id / (TSEQ * N_HEAD);

  const size_t row_stride = 3 * N_EMBD;
  const float* qrow = qkv + ((size_t)(b * TSEQ + q)) * row_stride + h * HS;
  const float* Kbase = qkv + ((size_t)b * TSEQ) * row_stride + N_EMBD + h * HS;
  const float* Vbase = qkv + ((size_t)b * TSEQ) * row_stride + 2 * N_EMBD + h * HS;

  const float scale = 0.125f;                      // 1/sqrt(64)
  float qd = qrow[lane] * scale;

  float m = -INFINITY, l = 0.f, o = 0.f;
  for (int j = 0; j <= q; ++j) {
    float kd = Kbase[(size_t)j * row_stride + lane];
    float s = qd * kd;
    // 64-lane sum reduction
#pragma unroll
    for (int off = 32; off >= 1; off >>= 1) s += __shfl_xor(s, off, 64);
    float vd = Vbase[(size_t)j * row_stride + lane];
    float mnew = fmaxf(m, s);
    float corr = __expf(m - mnew);     // 0 on first iter (m=-inf)
    float p = __expf(s - mnew);
    l = l * corr + p;
    o = o * corr + p * vd;
    m = mnew;
  }
  Y[((size_t)(b * TSEQ + q)) * N_EMBD + h * HS + lane] = o / l;
}

extern "C" void kernel_launch(void* const* d_in, const int* in_sizes, int n_in,
                              void* d_out, int out_size, void* d_ws, size_t ws_size,
                              hipStream_t stream) {
  const float* x      = (const float*)d_in[0];   // [2,2048,1024]
  const float* W_attn = (const float*)d_in[1];   // [1024,3072]
  const float* b_attn = (const float*)d_in[2];   // [3072]
  const float* W_proj = (const float*)d_in[3];   // [1024,1024]
  const float* b_proj = (const float*)d_in[4];   // [1024]
  float* out = (float*)d_out;                    // [2,2048,1024]

  float* qkv = (float*)d_ws;                               // 4096*3072 fp32 = 50.3MB
  float* y   = qkv + (size_t)BT * 3 * N_EMBD;              // 4096*1024 fp32 = 16.8MB

  // 1) qkv = x @ W_attn + b_attn
  {
    dim3 grid(3 * N_EMBD / TILE, BT / TILE);
    gemm_bias_f32<<<grid, 256, 0, stream>>>(x, W_attn, b_attn, qkv, BT, 3 * N_EMBD, N_EMBD);
  }
  // 2) y = causal_attention(qkv)
  {
    int nwaves = 2 * N_HEAD * TSEQ;       // 65536
    attn_causal_f32<<<nwaves / 4, 256, 0, stream>>>(qkv, y);
  }
  // 3) out = y @ W_proj + b_proj
  {
    dim3 grid(N_EMBD / TILE, BT / TILE);
    gemm_bias_f32<<<grid, 256, 0, stream>>>(y, W_proj, b_proj, out, BT, N_EMBD, N_EMBD);
  }
}

// Round 2
// 2367.206 us; speedup vs baseline: 2.2803x; 2.2803x over previous
//
#include <hip/hip_runtime.h>
#include <hip/hip_bf16.h>
#include <math.h>

#define N_EMBD 1024
#define N_HEAD 16
#define HS 64          // head size = wavefront size
#define BT 4096        // B*T rows
#define TSEQ 2048
#define QB 64          // q rows per block
#define KT 64          // k tile

// ---------------- Tiled fp32 GEMM with bias: C[M,N] = A[M,K] @ W[K,N] + bias[N]
#define TILE 64
#define BKK 32
__global__ __launch_bounds__(256) void gemm_bias_f32(
    const float* __restrict__ A, const float* __restrict__ W,
    const float* __restrict__ bias, float* __restrict__ C,
    int M, int N, int K) {
  __shared__ float As[BKK][TILE + 1];
  __shared__ float Bs[BKK][TILE + 1];
  const int bm = blockIdx.y * TILE;
  const int bn = blockIdx.x * TILE;
  const int tid = threadIdx.x;
  const int tn = tid & 15;   // 16 col groups
  const int tm = tid >> 4;   // 16 row groups
  float acc[4][4] = {};
  for (int k0 = 0; k0 < K; k0 += BKK) {
#pragma unroll
    for (int i = 0; i < 8; ++i) {
      int idx = tid + i * 256;        // 0..2047
      int m  = idx >> 5;              // /32
      int kk = idx & 31;
      As[kk][m] = A[(size_t)(bm + m) * K + k0 + kk];
    }
#pragma unroll
    for (int i = 0; i < 8; ++i) {
      int idx = tid + i * 256;
      int kk = idx >> 6;              // /64
      int n  = idx & 63;
      Bs[kk][n] = W[(size_t)(k0 + kk) * N + bn + n];
    }
    __syncthreads();
#pragma unroll
    for (int kk = 0; kk < BKK; ++kk) {
      float a[4], b[4];
#pragma unroll
      for (int i = 0; i < 4; ++i) a[i] = As[kk][tm * 4 + i];
#pragma unroll
      for (int j = 0; j < 4; ++j) b[j] = Bs[kk][tn * 4 + j];
#pragma unroll
      for (int i = 0; i < 4; ++i)
#pragma unroll
        for (int j = 0; j < 4; ++j) acc[i][j] += a[i] * b[j];
    }
    __syncthreads();
  }
#pragma unroll
  for (int i = 0; i < 4; ++i)
#pragma unroll
    for (int j = 0; j < 4; ++j) {
      int m = bm + tm * 4 + i, n = bn + tn * 4 + j;
      C[(size_t)m * N + n] = acc[i][j] + bias[n];
    }
}

// ---------------- Tiled flash attention, fp32 vector
// Block: 4 waves, 64 q-rows of one (b,h). Wave w owns rows q0+16w .. q0+16w+15.
// Phase A: lane = k-index (lane's K-row in regs), Q via LDS broadcast.
// Phase B: lane = d (V columns in regs), P via per-wave LDS transpose buffer.
__global__ __launch_bounds__(256) void attn_flash_f32(
    const float* __restrict__ qkv, float* __restrict__ Y) {
  __shared__ float Qs[QB][HS];        // pre-scaled by 1/8
  __shared__ float Ks[KT][HS];        // XOR-swizzled columns
  __shared__ float Vs[KT][HS];
  __shared__ float Ps[4][16][KT];     // per-wave P transpose buffer

  const int tid  = threadIdx.x;
  const int lane = tid & 63;
  const int w    = tid >> 6;
  const int q0   = blockIdx.x * QB;
  const int h    = blockIdx.y;
  const int b    = blockIdx.z;

  const size_t RS = 3 * N_EMBD;
  const float* base = qkv + (size_t)b * TSEQ * RS;

  // stage Q (pre-scaled). thread t: rows (t>>4)+16i, col4 = t&15
  {
    const float* Qg = base + (size_t)q0 * RS + h * HS;
#pragma unroll
    for (int i = 0; i < 4; ++i) {
      int r = (tid >> 4) + i * 16;
      int c = (tid & 15) * 4;
      float4 v = *(const float4*)(Qg + (size_t)r * RS + c);
      v.x *= 0.125f; v.y *= 0.125f; v.z *= 0.125f; v.w *= 0.125f;
      *(float4*)&Qs[r][c] = v;
    }
  }

  float m[16], l[16], corr[16], o[16];
#pragma unroll
  for (int r = 0; r < 16; ++r) { m[r] = -INFINITY; l[r] = 0.f; o[r] = 0.f; }

  const int ntiles = q0 / KT + 1;
  for (int t = 0; t < ntiles; ++t) {
    const int kb = t * KT;
    __syncthreads();   // prior tile's readers done before overwrite (also orders Q staging)
    // stage K (swizzled) and V
    const float* Kg = base + (size_t)kb * RS + N_EMBD + h * HS;
    const float* Vg = Kg + N_EMBD;
#pragma unroll
    for (int i = 0; i < 4; ++i) {
      int r  = (tid >> 4) + i * 16;
      int c  = (tid & 15) * 4;
      float4 kv = *(const float4*)(Kg + (size_t)r * RS + c);
      int cs = c ^ ((r & 7) << 2);
      *(float4*)&Ks[r][cs] = kv;
      float4 vv = *(const float4*)(Vg + (size_t)r * RS + c);
      *(float4*)&Vs[r][c] = vv;
    }
    __syncthreads();

    // ---- Phase A: QK^T + online softmax. lane = k-index.
    float kr[64];
#pragma unroll
    for (int c4 = 0; c4 < 16; ++c4) {
      int cs = (c4 * 4) ^ ((lane & 7) << 2);
      float4 v = *(const float4*)&Ks[lane][cs];
      kr[c4 * 4 + 0] = v.x; kr[c4 * 4 + 1] = v.y;
      kr[c4 * 4 + 2] = v.z; kr[c4 * 4 + 3] = v.w;
    }
    const bool last = (t == ntiles - 1);
#pragma unroll
    for (int r = 0; r < 16; ++r) {
      float s0 = 0.f, s1 = 0.f, s2 = 0.f, s3 = 0.f;
#pragma unroll
      for (int c4 = 0; c4 < 16; ++c4) {
        float4 qv = *(const float4*)&Qs[w * 16 + r][c4 * 4];
        s0 += qv.x * kr[c4 * 4 + 0];
        s1 += qv.y * kr[c4 * 4 + 1];
        s2 += qv.z * kr[c4 * 4 + 2];
        s3 += qv.w * kr[c4 * 4 + 3];
      }
      float s = (s0 + s1) + (s2 + s3);
      if (last) {
        if (kb + lane > q0 + w * 16 + r) s = -3.0e38f;   // causal mask
      }
      float smax = s;
#pragma unroll
      for (int off = 32; off >= 1; off >>= 1) smax = fmaxf(smax, __shfl_xor(smax, off, 64));
      float mnew = fmaxf(m[r], smax);
      float cr = __expf(m[r] - mnew);
      float p  = __expf(s - mnew);
      float ps = p;
#pragma unroll
      for (int off = 32; off >= 1; off >>= 1) ps += __shfl_xor(ps, off, 64);
      l[r] = l[r] * cr + ps;
      m[r] = mnew;
      corr[r] = cr;
      Ps[w][r][lane] = p;
    }
    __builtin_amdgcn_sched_barrier(0);  // keep vr loads out of phase A (register pressure)

    // ---- Phase B: PV. lane = d. V columns in regs, reused across 16 rows.
    float vr[64];
#pragma unroll
    for (int j = 0; j < 64; ++j) vr[j] = Vs[j][lane];
#pragma unroll
    for (int r = 0; r < 16; ++r) {
      float a0 = 0.f, a1 = 0.f, a2 = 0.f, a3 = 0.f;
#pragma unroll
      for (int j4 = 0; j4 < 16; ++j4) {
        float4 pv = *(const float4*)&Ps[w][r][j4 * 4];
        a0 += pv.x * vr[j4 * 4 + 0];
        a1 += pv.y * vr[j4 * 4 + 1];
        a2 += pv.z * vr[j4 * 4 + 2];
        a3 += pv.w * vr[j4 * 4 + 3];
      }
      o[r] = o[r] * corr[r] + ((a0 + a1) + (a2 + a3));
    }
  }

  // epilogue: coalesced write
#pragma unroll
  for (int r = 0; r < 16; ++r) {
    int q = q0 + w * 16 + r;
    Y[((size_t)(b * TSEQ + q)) * N_EMBD + h * HS + lane] = o[r] / l[r];
  }
}

extern "C" void kernel_launch(void* const* d_in, const int* in_sizes, int n_in,
                              void* d_out, int out_size, void* d_ws, size_t ws_size,
                              hipStream_t stream) {
  const float* x      = (const float*)d_in[0];   // [2,2048,1024]
  const float* W_attn = (const float*)d_in[1];   // [1024,3072]
  const float* b_attn = (const float*)d_in[2];   // [3072]
  const float* W_proj = (const float*)d_in[3];   // [1024,1024]
  const float* b_proj = (const float*)d_in[4];   // [1024]
  float* out = (float*)d_out;                    // [2,2048,1024]

  float* qkv = (float*)d_ws;                               // 4096*3072 fp32
  float* y   = qkv + (size_t)BT * 3 * N_EMBD;              // 4096*1024 fp32

  // 1) qkv = x @ W_attn + b_attn
  {
    dim3 grid(3 * N_EMBD / TILE, BT / TILE);
    gemm_bias_f32<<<grid, 256, 0, stream>>>(x, W_attn, b_attn, qkv, BT, 3 * N_EMBD, N_EMBD);
  }
  // 2) y = causal_attention(qkv)
  {
    dim3 grid(TSEQ / QB, N_HEAD, 2);
    attn_flash_f32<<<grid, 256, 0, stream>>>(qkv, y);
  }
  // 3) out = y @ W_proj + b_proj
  {
    dim3 grid(N_EMBD / TILE, BT / TILE);
    gemm_bias_f32<<<grid, 256, 0, stream>>>(y, W_proj, b_proj, out, BT, N_EMBD, N_EMBD);
  }
}

// Round 3
// 892.913 us; speedup vs baseline: 6.0454x; 2.6511x over previous
//
#include <hip/hip_runtime.h>
#include <hip/hip_bf16.h>
#include <math.h>

#define N_EMBD 1024
#define N_HEAD 16
#define HS 64
#define BT 4096
#define TSEQ 2048

typedef float f32x4 __attribute__((ext_vector_type(4)));
typedef short bf16x8 __attribute__((ext_vector_type(8)));

static __device__ __forceinline__ unsigned short f2bf(float f) {
  union { float f; unsigned int u; } c; c.f = f;
  unsigned int r = c.u + 0x7FFFu + ((c.u >> 16) & 1u);   // RNE
  return (unsigned short)(r >> 16);
}

// ---------------- fp32 GEMM producing head-split bf16 Q/K/V
// qkv = x @ W_attn + b_attn ; writes Qb[b,h,t,d]*0.125, Kb[b,h,t,d], Vt[b,h,d,t]
#define TILE 64
#define BKK 32
__global__ __launch_bounds__(256) void gemm_qkv_f32(
    const float* __restrict__ A, const float* __restrict__ W,
    const float* __restrict__ bias,
    unsigned short* __restrict__ Qb, unsigned short* __restrict__ Kb,
    unsigned short* __restrict__ Vt) {
  __shared__ float As[BKK][TILE + 1];
  __shared__ float Bs[BKK][TILE + 1];
  const int bm = blockIdx.y * TILE;
  const int bn = blockIdx.x * TILE;
  const int tid = threadIdx.x;
  const int tn = tid & 15;
  const int tm = tid >> 4;
  const int K = N_EMBD, N = 3 * N_EMBD;
  float acc[4][4] = {};
  for (int k0 = 0; k0 < K; k0 += BKK) {
#pragma unroll
    for (int i = 0; i < 8; ++i) {
      int idx = tid + i * 256;
      int m = idx >> 5, kk = idx & 31;
      As[kk][m] = A[(size_t)(bm + m) * K + k0 + kk];
    }
#pragma unroll
    for (int i = 0; i < 8; ++i) {
      int idx = tid + i * 256;
      int kk = idx >> 6, n = idx & 63;
      Bs[kk][n] = W[(size_t)(k0 + kk) * N + bn + n];
    }
    __syncthreads();
#pragma unroll
    for (int kk = 0; kk < BKK; ++kk) {
      float a[4], b[4];
#pragma unroll
      for (int i = 0; i < 4; ++i) a[i] = As[kk][tm * 4 + i];
#pragma unroll
      for (int j = 0; j < 4; ++j) b[j] = Bs[kk][tn * 4 + j];
#pragma unroll
      for (int i = 0; i < 4; ++i)
#pragma unroll
        for (int j = 0; j < 4; ++j) acc[i][j] += a[i] * b[j];
    }
    __syncthreads();
  }
  // epilogue: tile is entirely one (sector, head)
  const int sector = bn >> 10;            // 0=Q 1=K 2=V
  const int h = (bn & 1023) >> 6;
#pragma unroll
  for (int i = 0; i < 4; ++i) {
    int m = bm + tm * 4 + i;
    int b = m >> 11, t = m & 2047;
    size_t rowQK = ((size_t)(b * 16 + h) * TSEQ + t) * HS;   // + d
    if (sector == 0) {
      ushort4 uv;
      uv.x = f2bf((acc[i][0] + bias[bn + tn * 4 + 0]) * 0.125f);
      uv.y = f2bf((acc[i][1] + bias[bn + tn * 4 + 1]) * 0.125f);
      uv.z = f2bf((acc[i][2] + bias[bn + tn * 4 + 2]) * 0.125f);
      uv.w = f2bf((acc[i][3] + bias[bn + tn * 4 + 3]) * 0.125f);
      *(ushort4*)(Qb + rowQK + ((bn & 63) + tn * 4)) = uv;
    } else if (sector == 1) {
      ushort4 uv;
      uv.x = f2bf(acc[i][0] + bias[bn + tn * 4 + 0]);
      uv.y = f2bf(acc[i][1] + bias[bn + tn * 4 + 1]);
      uv.z = f2bf(acc[i][2] + bias[bn + tn * 4 + 2]);
      uv.w = f2bf(acc[i][3] + bias[bn + tn * 4 + 3]);
      *(ushort4*)(Kb + rowQK + ((bn & 63) + tn * 4)) = uv;
    } else {
#pragma unroll
      for (int j = 0; j < 4; ++j) {
        int d = (bn & 63) + tn * 4 + j;
        Vt[((size_t)(b * 16 + h) * HS + d) * TSEQ + t] =
            f2bf(acc[i][j] + bias[bn + tn * 4 + j]);
      }
    }
  }
}

// ---------------- plain fp32 GEMM with bias (projection)
__global__ __launch_bounds__(256) void gemm_bias_f32(
    const float* __restrict__ A, const float* __restrict__ W,
    const float* __restrict__ bias, float* __restrict__ C,
    int M, int N, int K) {
  __shared__ float As[BKK][TILE + 1];
  __shared__ float Bs[BKK][TILE + 1];
  const int bm = blockIdx.y * TILE;
  const int bn = blockIdx.x * TILE;
  const int tid = threadIdx.x;
  const int tn = tid & 15;
  const int tm = tid >> 4;
  float acc[4][4] = {};
  for (int k0 = 0; k0 < K; k0 += BKK) {
#pragma unroll
    for (int i = 0; i < 8; ++i) {
      int idx = tid + i * 256;
      int m = idx >> 5, kk = idx & 31;
      As[kk][m] = A[(size_t)(bm + m) * K + k0 + kk];
    }
#pragma unroll
    for (int i = 0; i < 8; ++i) {
      int idx = tid + i * 256;
      int kk = idx >> 6, n = idx & 63;
      Bs[kk][n] = W[(size_t)(k0 + kk) * N + bn + n];
    }
    __syncthreads();
#pragma unroll
    for (int kk = 0; kk < BKK; ++kk) {
      float a[4], b[4];
#pragma unroll
      for (int i = 0; i < 4; ++i) a[i] = As[kk][tm * 4 + i];
#pragma unroll
      for (int j = 0; j < 4; ++j) b[j] = Bs[kk][tn * 4 + j];
#pragma unroll
      for (int i = 0; i < 4; ++i)
#pragma unroll
        for (int j = 0; j < 4; ++j) acc[i][j] += a[i] * b[j];
    }
    __syncthreads();
  }
#pragma unroll
  for (int i = 0; i < 4; ++i)
#pragma unroll
    for (int j = 0; j < 4; ++j) {
      int m = bm + tm * 4 + i, n = bn + tn * 4 + j;
      C[(size_t)m * N + n] = acc[i][j] + bias[n];
    }
}

// ---------------- MFMA flash attention (bf16 inputs, fp32 accum)
// 4 independent waves/block; wave owns 16 q-rows. K/V frags read from global (L2).
// MFMA 16x16x32: A row=lane&15,k=(lane>>4)*8+j ; B col=lane&15,k=(lane>>4)*8+j ;
// C/D col=lane&15, row=(lane>>4)*4+reg.
__global__ __launch_bounds__(256) void attn_mfma(
    const unsigned short* __restrict__ Qb, const unsigned short* __restrict__ Kb,
    const unsigned short* __restrict__ Vt, float* __restrict__ Y) {
  __shared__ unsigned short Plds[4][16][72];   // per-wave, padded (144B rows)

  const int tid  = threadIdx.x;
  const int lane = tid & 63;
  const int w    = tid >> 6;
  const int lrow = lane & 15;
  const int lhi  = lane >> 4;
  const int q0w  = blockIdx.x * 64 + w * 16;
  const int h    = blockIdx.y;
  const int b    = blockIdx.z;

  const unsigned short* Qh = Qb + (size_t)(b * 16 + h) * TSEQ * HS;
  const unsigned short* Kh = Kb + (size_t)(b * 16 + h) * TSEQ * HS;
  const unsigned short* Vh = Vt + (size_t)(b * 16 + h) * HS * TSEQ;

  // Q fragments (stay in regs for whole kernel)
  bf16x8 aq0 = *(const bf16x8*)(Qh + (size_t)(q0w + lrow) * HS + lhi * 8);
  bf16x8 aq1 = *(const bf16x8*)(Qh + (size_t)(q0w + lrow) * HS + 32 + lhi * 8);

  f32x4 o[4];
  float m_[4], l_[4];
#pragma unroll
  for (int r = 0; r < 4; ++r) { m_[r] = -INFINITY; l_[r] = 0.f; }
#pragma unroll
  for (int ds = 0; ds < 4; ++ds) o[ds] = (f32x4){0.f, 0.f, 0.f, 0.f};

  const int nblk = q0w / 64 + 1;
  for (int blk = 0; blk < nblk; ++blk) {
    const int kb = blk * 64;
    const bool lastb = (blk == nblk - 1);

    // ---- QK^T: 4 sub-tiles of 16 k
    f32x4 sacc[4];
#pragma unroll
    for (int s = 0; s < 4; ++s) {
      const int kt = kb + 16 * s;
      bf16x8 bk0 = *(const bf16x8*)(Kh + (size_t)(kt + lrow) * HS + lhi * 8);
      bf16x8 bk1 = *(const bf16x8*)(Kh + (size_t)(kt + lrow) * HS + 32 + lhi * 8);
      f32x4 z = (f32x4){0.f, 0.f, 0.f, 0.f};
      z = __builtin_amdgcn_mfma_f32_16x16x32_bf16(aq0, bk0, z, 0, 0, 0);
      z = __builtin_amdgcn_mfma_f32_16x16x32_bf16(aq1, bk1, z, 0, 0, 0);
      sacc[s] = z;
    }
    if (lastb) {
#pragma unroll
      for (int s = 0; s < 4; ++s) {
        int kg = kb + 16 * s + lrow;
#pragma unroll
        for (int r = 0; r < 4; ++r) {
          int qg = q0w + lhi * 4 + r;
          if (kg > qg) sacc[s][r] = -3.0e38f;
        }
      }
    }

    // ---- online softmax over the 64-wide block (per q-row = per reg)
    float corr[4];
#pragma unroll
    for (int r = 0; r < 4; ++r) {
      float mx = fmaxf(fmaxf(sacc[0][r], sacc[1][r]), fmaxf(sacc[2][r], sacc[3][r]));
#pragma unroll
      for (int off = 1; off <= 8; off <<= 1) mx = fmaxf(mx, __shfl_xor(mx, off));
      float mnew = fmaxf(m_[r], mx);
      float cr = __expf(m_[r] - mnew);
      float ps = 0.f;
#pragma unroll
      for (int s = 0; s < 4; ++s) {
        float p = __expf(sacc[s][r] - mnew);
        ps += p;
        Plds[w][lhi * 4 + r][s * 16 + lrow] = f2bf(p);
      }
#pragma unroll
      for (int off = 1; off <= 8; off <<= 1) ps += __shfl_xor(ps, off);
      l_[r] = l_[r] * cr + ps;
      m_[r] = mnew;
      corr[r] = cr;
    }
#pragma unroll
    for (int ds = 0; ds < 4; ++ds)
#pragma unroll
      for (int r = 0; r < 4; ++r) o[ds][r] *= corr[r];

    // ---- PV: O += P[16x64] @ V[64x64]
#pragma unroll
    for (int ks = 0; ks < 2; ++ks) {
      bf16x8 pa = *(const bf16x8*)&Plds[w][lrow][ks * 32 + lhi * 8];
#pragma unroll
      for (int ds = 0; ds < 4; ++ds) {
        bf16x8 pv = *(const bf16x8*)(Vh + (size_t)(ds * 16 + lrow) * TSEQ
                                        + kb + ks * 32 + lhi * 8);
        o[ds] = __builtin_amdgcn_mfma_f32_16x16x32_bf16(pa, pv, o[ds], 0, 0, 0);
      }
    }
  }

  // ---- epilogue
#pragma unroll
  for (int ds = 0; ds < 4; ++ds)
#pragma unroll
    for (int r = 0; r < 4; ++r) {
      int q = q0w + lhi * 4 + r;
      Y[((size_t)(b * TSEQ + q)) * N_EMBD + h * HS + ds * 16 + lrow] =
          o[ds][r] / l_[r];
    }
}

extern "C" void kernel_launch(void* const* d_in, const int* in_sizes, int n_in,
                              void* d_out, int out_size, void* d_ws, size_t ws_size,
                              hipStream_t stream) {
  const float* x      = (const float*)d_in[0];
  const float* W_attn = (const float*)d_in[1];
  const float* b_attn = (const float*)d_in[2];
  const float* W_proj = (const float*)d_in[3];
  const float* b_proj = (const float*)d_in[4];
  float* out = (float*)d_out;

  unsigned short* Qb = (unsigned short*)d_ws;          // 4.19M elems
  unsigned short* Kb = Qb + (size_t)BT * N_EMBD;
  unsigned short* Vt = Kb + (size_t)BT * N_EMBD;
  float* y = (float*)(Vt + (size_t)BT * N_EMBD);       // 16.8MB fp32

  // 1) qkv GEMM -> head-split bf16 Q/K/V (V transposed)
  {
    dim3 grid(3 * N_EMBD / TILE, BT / TILE);
    gemm_qkv_f32<<<grid, 256, 0, stream>>>(x, W_attn, b_attn, Qb, Kb, Vt);
  }
  // 2) MFMA flash attention -> y (fp32)
  {
    dim3 grid(TSEQ / 64, N_HEAD, 2);
    attn_mfma<<<grid, 256, 0, stream>>>(Qb, Kb, Vt, y);
  }
  // 3) out = y @ W_proj + b_proj
  {
    dim3 grid(N_EMBD / TILE, BT / TILE);
    gemm_bias_f32<<<grid, 256, 0, stream>>>(y, W_proj, b_proj, out, BT, N_EMBD, N_EMBD);
  }
}

// Round 4
// 302.894 us; speedup vs baseline: 17.8214x; 2.9479x over previous
//
#include <hip/hip_runtime.h>
#include <hip/hip_bf16.h>
#include <math.h>

#define N_EMBD 1024
#define N_HEAD 16
#define HS 64
#define BT 4096
#define TSEQ 2048

typedef float f32x4 __attribute__((ext_vector_type(4)));
typedef short bf16x8 __attribute__((ext_vector_type(8)));
typedef unsigned short u16;

static __device__ __forceinline__ u16 f2bf(float f) {
  union { float f; unsigned int u; } c; c.f = f;
  unsigned int r = c.u + 0x7FFFu + ((c.u >> 16) & 1u);   // RNE
  return (u16)(r >> 16);
}

// ---------------- prep: fp32 -> bf16 elementwise (x)
__global__ __launch_bounds__(256) void cvt_bf16(const float* __restrict__ in,
                                                u16* __restrict__ out, int n4) {
  int i = blockIdx.x * 256 + threadIdx.x;
  if (i < n4) {
    float4 v = ((const float4*)in)[i];
    ushort4 o;
    o.x = f2bf(v.x); o.y = f2bf(v.y); o.z = f2bf(v.z); o.w = f2bf(v.w);
    ((ushort4*)out)[i] = o;
  }
}

// ---------------- prep: W[K][N] fp32 -> Wt[N][K] bf16 (32x32 LDS transpose)
__global__ __launch_bounds__(256) void transpose_cvt(const float* __restrict__ W,
                                                     u16* __restrict__ Wt,
                                                     int K, int N) {
  __shared__ u16 Ls[32][36];
  const int n0 = blockIdx.x * 32, k0 = blockIdx.y * 32;
  const int t = threadIdx.x;
  {
    int kk = t >> 3, nn4 = (t & 7) * 4;
    float4 v = *(const float4*)(W + (size_t)(k0 + kk) * N + n0 + nn4);
    Ls[kk][nn4 + 0] = f2bf(v.x); Ls[kk][nn4 + 1] = f2bf(v.y);
    Ls[kk][nn4 + 2] = f2bf(v.z); Ls[kk][nn4 + 3] = f2bf(v.w);
  }
  __syncthreads();
  {
    int nn = t >> 3, kk4 = (t & 7) * 4;
    ushort4 o;
    o.x = Ls[kk4 + 0][nn]; o.y = Ls[kk4 + 1][nn];
    o.z = Ls[kk4 + 2][nn]; o.w = Ls[kk4 + 3][nn];
    *(ushort4*)(Wt + (size_t)(n0 + nn) * K + k0 + kk4) = o;
  }
}

// ---------------- bf16 MFMA GEMM core (m97 structure)
// A[M][K] bf16 row-major, Bt[N][K] bf16 row-major (= B^T). Tile 128x128, BK=32.
// 4 waves (2x2), each 64x64 out = 4x4 frags of 16x16x32. LDS dbuf, global_load_lds,
// XOR swizzle chunk ^= (row>>1)&3 (pre-swizzled source, swizzled ds_read).
#define BKS 32

__device__ __forceinline__ int swz(int row, int c) {
  return row * 4 + (c ^ ((row >> 1) & 3));
}

__device__ __forceinline__ void stage128x32(const u16* __restrict__ G, int ldk,
                                            u16* lds, int w, int lane) {
#pragma unroll
  for (int i = 0; i < 2; ++i) {
    int s = i * 256 + w * 64 + lane;
    int row = s >> 2, c = s & 3;
    int csrc = c ^ ((row >> 1) & 3);
    const u16* src = G + (size_t)row * ldk + csrc * 8;
    u16* dst = lds + (size_t)(i * 256 + w * 64) * 8;   // wave-uniform base
    __builtin_amdgcn_global_load_lds(
        (const __attribute__((address_space(1))) void*)src,
        (__attribute__((address_space(3))) void*)dst, 16, 0, 0);
  }
}

#define GEMM_MAIN_LOOP(Aptr, Bptr, Kdim)                                        \
  __shared__ u16 sm[2][2][128 * BKS];                                           \
  const int tid = threadIdx.x, lane = tid & 63, w = tid >> 6;                   \
  const int wr = w >> 1, wc = w & 1, lrow = lane & 15, lhi = lane >> 4;         \
  const int bm = blockIdx.y * 128, bn = blockIdx.x * 128;                       \
  f32x4 acc[4][4];                                                              \
  _Pragma("unroll") for (int i = 0; i < 4; ++i)                                 \
      _Pragma("unroll") for (int j = 0; j < 4; ++j)                             \
          acc[i][j] = (f32x4){0.f, 0.f, 0.f, 0.f};                              \
  stage128x32(Aptr + (size_t)bm * Kdim, Kdim, sm[0][0], w, lane);               \
  stage128x32(Bptr + (size_t)bn * Kdim, Kdim, sm[0][1], w, lane);               \
  __syncthreads();                                                              \
  const int NT = Kdim / BKS;                                                    \
  for (int t = 0; t < NT; ++t) {                                                \
    int cur = t & 1, nxt = cur ^ 1;                                             \
    if (t + 1 < NT) {                                                           \
      stage128x32(Aptr + (size_t)bm * Kdim + (t + 1) * BKS, Kdim, sm[nxt][0],   \
                  w, lane);                                                     \
      stage128x32(Bptr + (size_t)bn * Kdim + (t + 1) * BKS, Kdim, sm[nxt][1],   \
                  w, lane);                                                     \
    }                                                                           \
    const u16* As = sm[cur][0];                                                 \
    const u16* Bs = sm[cur][1];                                                 \
    bf16x8 af[4], bf[4];                                                        \
    _Pragma("unroll") for (int mi = 0; mi < 4; ++mi) {                          \
      int row = wr * 64 + mi * 16 + lrow;                                       \
      af[mi] = *(const bf16x8*)(As + (size_t)swz(row, lhi) * 8);                \
    }                                                                           \
    _Pragma("unroll") for (int nj = 0; nj < 4; ++nj) {                          \
      int row = wc * 64 + nj * 16 + lrow;                                       \
      bf[nj] = *(const bf16x8*)(Bs + (size_t)swz(row, lhi) * 8);                \
    }                                                                           \
    _Pragma("unroll") for (int mi = 0; mi < 4; ++mi)                            \
        _Pragma("unroll") for (int nj = 0; nj < 4; ++nj)                        \
            acc[mi][nj] = __builtin_amdgcn_mfma_f32_16x16x32_bf16(              \
                af[mi], bf[nj], acc[mi][nj], 0, 0, 0);                          \
    __syncthreads();                                                            \
  }

// QKV GEMM: A=xb[4096][1024], B=Wat[3072][1024]. Epilogue -> Qb/Kb/Vt bf16.
__global__ __launch_bounds__(256) void gemm_qkv_bf16(
    const u16* __restrict__ Ab, const u16* __restrict__ Btr,
    const float* __restrict__ bias,
    u16* __restrict__ Qb, u16* __restrict__ Kb, u16* __restrict__ Vt) {
  GEMM_MAIN_LOOP(Ab, Btr, N_EMBD)
  const int sector = bn >> 10;                    // 0=Q 1=K 2=V
#pragma unroll
  for (int nj = 0; nj < 4; ++nj) {
    int n = bn + wc * 64 + nj * 16 + lrow;
    int h = (n & 1023) >> 6, d = n & 63;
    float bv = bias[n];
#pragma unroll
    for (int mi = 0; mi < 4; ++mi) {
      int mbase = bm + wr * 64 + mi * 16 + lhi * 4;
      int bb_ = mbase >> 11, tt = mbase & 2047;
      if (sector == 0) {
#pragma unroll
        for (int r = 0; r < 4; ++r)
          Qb[((size_t)(bb_ * 16 + h) * TSEQ + tt + r) * HS + d] =
              f2bf((acc[mi][nj][r] + bv) * 0.125f);
      } else if (sector == 1) {
#pragma unroll
        for (int r = 0; r < 4; ++r)
          Kb[((size_t)(bb_ * 16 + h) * TSEQ + tt + r) * HS + d] =
              f2bf(acc[mi][nj][r] + bv);
      } else {
        ushort4 o;
        o.x = f2bf(acc[mi][nj][0] + bv); o.y = f2bf(acc[mi][nj][1] + bv);
        o.z = f2bf(acc[mi][nj][2] + bv); o.w = f2bf(acc[mi][nj][3] + bv);
        *(ushort4*)(Vt + ((size_t)(bb_ * 16 + h) * HS + d) * TSEQ + tt) = o;
      }
    }
  }
}

// Proj GEMM: A=yb[4096][1024], B=Wpt[1024][1024]. Epilogue -> fp32 out + bias.
__global__ __launch_bounds__(256) void gemm_proj_bf16(
    const u16* __restrict__ Ab, const u16* __restrict__ Btr,
    const float* __restrict__ bias, float* __restrict__ C) {
  GEMM_MAIN_LOOP(Ab, Btr, N_EMBD)
#pragma unroll
  for (int nj = 0; nj < 4; ++nj) {
    int n = bn + wc * 64 + nj * 16 + lrow;
    float bv = bias[n];
#pragma unroll
    for (int mi = 0; mi < 4; ++mi) {
      int mbase = bm + wr * 64 + mi * 16 + lhi * 4;
#pragma unroll
      for (int r = 0; r < 4; ++r)
        C[(size_t)(mbase + r) * N_EMBD + n] = acc[mi][nj][r] + bv;
    }
  }
}

// ---------------- MFMA flash attention (unchanged core; emits bf16 y)
__global__ __launch_bounds__(256) void attn_mfma(
    const u16* __restrict__ Qb, const u16* __restrict__ Kb,
    const u16* __restrict__ Vt, u16* __restrict__ Y) {
  __shared__ u16 Plds[4][16][72];

  const int tid  = threadIdx.x;
  const int lane = tid & 63;
  const int w    = tid >> 6;
  const int lrow = lane & 15;
  const int lhi  = lane >> 4;
  const int q0w  = blockIdx.x * 64 + w * 16;
  const int h    = blockIdx.y;
  const int b    = blockIdx.z;

  const u16* Qh = Qb + (size_t)(b * 16 + h) * TSEQ * HS;
  const u16* Kh = Kb + (size_t)(b * 16 + h) * TSEQ * HS;
  const u16* Vh = Vt + (size_t)(b * 16 + h) * HS * TSEQ;

  bf16x8 aq0 = *(const bf16x8*)(Qh + (size_t)(q0w + lrow) * HS + lhi * 8);
  bf16x8 aq1 = *(const bf16x8*)(Qh + (size_t)(q0w + lrow) * HS + 32 + lhi * 8);

  f32x4 o[4];
  float m_[4], l_[4];
#pragma unroll
  for (int r = 0; r < 4; ++r) { m_[r] = -INFINITY; l_[r] = 0.f; }
#pragma unroll
  for (int ds = 0; ds < 4; ++ds) o[ds] = (f32x4){0.f, 0.f, 0.f, 0.f};

  const int nblk = q0w / 64 + 1;
  for (int blk = 0; blk < nblk; ++blk) {
    const int kb = blk * 64;
    const bool lastb = (blk == nblk - 1);

    f32x4 sacc[4];
#pragma unroll
    for (int s = 0; s < 4; ++s) {
      const int kt = kb + 16 * s;
      bf16x8 bk0 = *(const bf16x8*)(Kh + (size_t)(kt + lrow) * HS + lhi * 8);
      bf16x8 bk1 = *(const bf16x8*)(Kh + (size_t)(kt + lrow) * HS + 32 + lhi * 8);
      f32x4 z = (f32x4){0.f, 0.f, 0.f, 0.f};
      z = __builtin_amdgcn_mfma_f32_16x16x32_bf16(aq0, bk0, z, 0, 0, 0);
      z = __builtin_amdgcn_mfma_f32_16x16x32_bf16(aq1, bk1, z, 0, 0, 0);
      sacc[s] = z;
    }
    if (lastb) {
#pragma unroll
      for (int s = 0; s < 4; ++s) {
        int kg = kb + 16 * s + lrow;
#pragma unroll
        for (int r = 0; r < 4; ++r) {
          int qg = q0w + lhi * 4 + r;
          if (kg > qg) sacc[s][r] = -3.0e38f;
        }
      }
    }

    float corr[4];
#pragma unroll
    for (int r = 0; r < 4; ++r) {
      float mx = fmaxf(fmaxf(sacc[0][r], sacc[1][r]), fmaxf(sacc[2][r], sacc[3][r]));
#pragma unroll
      for (int off = 1; off <= 8; off <<= 1) mx = fmaxf(mx, __shfl_xor(mx, off));
      float mnew = fmaxf(m_[r], mx);
      float cr = __expf(m_[r] - mnew);
      float ps = 0.f;
#pragma unroll
      for (int s = 0; s < 4; ++s) {
        float p = __expf(sacc[s][r] - mnew);
        ps += p;
        Plds[w][lhi * 4 + r][s * 16 + lrow] = f2bf(p);
      }
#pragma unroll
      for (int off = 1; off <= 8; off <<= 1) ps += __shfl_xor(ps, off);
      l_[r] = l_[r] * cr + ps;
      m_[r] = mnew;
      corr[r] = cr;
    }
#pragma unroll
    for (int ds = 0; ds < 4; ++ds)
#pragma unroll
      for (int r = 0; r < 4; ++r) o[ds][r] *= corr[r];

#pragma unroll
    for (int ks = 0; ks < 2; ++ks) {
      bf16x8 pa = *(const bf16x8*)&Plds[w][lrow][ks * 32 + lhi * 8];
#pragma unroll
      for (int ds = 0; ds < 4; ++ds) {
        bf16x8 pv = *(const bf16x8*)(Vh + (size_t)(ds * 16 + lrow) * TSEQ
                                        + kb + ks * 32 + lhi * 8);
        o[ds] = __builtin_amdgcn_mfma_f32_16x16x32_bf16(pa, pv, o[ds], 0, 0, 0);
      }
    }
  }

#pragma unroll
  for (int ds = 0; ds < 4; ++ds)
#pragma unroll
    for (int r = 0; r < 4; ++r) {
      int q = q0w + lhi * 4 + r;
      Y[((size_t)(b * TSEQ + q)) * N_EMBD + h * HS + ds * 16 + lrow] =
          f2bf(o[ds][r] / l_[r]);
    }
}

extern "C" void kernel_launch(void* const* d_in, const int* in_sizes, int n_in,
                              void* d_out, int out_size, void* d_ws, size_t ws_size,
                              hipStream_t stream) {
  const float* x      = (const float*)d_in[0];
  const float* W_attn = (const float*)d_in[1];
  const float* b_attn = (const float*)d_in[2];
  const float* W_proj = (const float*)d_in[3];
  const float* b_proj = (const float*)d_in[4];
  float* out = (float*)d_out;

  u16* xb  = (u16*)d_ws;                           // 4096*1024
  u16* Wat = xb  + (size_t)BT * N_EMBD;            // 3072*1024
  u16* Wpt = Wat + (size_t)3 * N_EMBD * N_EMBD;    // 1024*1024
  u16* Qb  = Wpt + (size_t)N_EMBD * N_EMBD;        // 4096*1024
  u16* Kb  = Qb  + (size_t)BT * N_EMBD;
  u16* Vt  = Kb  + (size_t)BT * N_EMBD;
  u16* yb  = Vt  + (size_t)BT * N_EMBD;            // 4096*1024

  // prep: x->bf16; W_attn,W_proj -> bf16 transposed [N][K]
  cvt_bf16<<<(BT * N_EMBD / 4 + 255) / 256, 256, 0, stream>>>(x, xb, BT * N_EMBD / 4);
  {
    dim3 g1(3 * N_EMBD / 32, N_EMBD / 32);
    transpose_cvt<<<g1, 256, 0, stream>>>(W_attn, Wat, N_EMBD, 3 * N_EMBD);
    dim3 g2(N_EMBD / 32, N_EMBD / 32);
    transpose_cvt<<<g2, 256, 0, stream>>>(W_proj, Wpt, N_EMBD, N_EMBD);
  }
  // 1) QKV GEMM (bf16 MFMA) -> head-split Q/K/Vt
  {
    dim3 grid(3 * N_EMBD / 128, BT / 128);
    gemm_qkv_bf16<<<grid, 256, 0, stream>>>(xb, Wat, b_attn, Qb, Kb, Vt);
  }
  // 2) MFMA flash attention -> yb (bf16)
  {
    dim3 grid(TSEQ / 64, N_HEAD, 2);
    attn_mfma<<<grid, 256, 0, stream>>>(Qb, Kb, Vt, yb);
  }
  // 3) out = yb @ Wpt^T + b_proj (fp32 out)
  {
    dim3 grid(N_EMBD / 128, BT / 128);
    gemm_proj_bf16<<<grid, 256, 0, stream>>>(yb, Wpt, b_proj, out);
  }
}

// Round 5
// 196.706 us; speedup vs baseline: 27.4420x; 1.5398x over previous
//
#include <hip/hip_runtime.h>
#include <hip/hip_bf16.h>
#include <math.h>

#define N_EMBD 1024
#define N_HEAD 16
#define HS 64
#define BT 4096
#define TSEQ 2048

typedef float f32x4 __attribute__((ext_vector_type(4)));
typedef short bf16x8 __attribute__((ext_vector_type(8)));
typedef unsigned short u16;

static __device__ __forceinline__ u16 f2bf(float f) {
  union { float f; unsigned int u; } c; c.f = f;
  unsigned int r = c.u + 0x7FFFu + ((c.u >> 16) & 1u);   // RNE
  return (u16)(r >> 16);
}

// ---------------- prep: fp32 -> bf16 elementwise (x)
__global__ __launch_bounds__(256) void cvt_bf16(const float* __restrict__ in,
                                                u16* __restrict__ out, int n4) {
  int i = blockIdx.x * 256 + threadIdx.x;
  if (i < n4) {
    float4 v = ((const float4*)in)[i];
    ushort4 o;
    o.x = f2bf(v.x); o.y = f2bf(v.y); o.z = f2bf(v.z); o.w = f2bf(v.w);
    ((ushort4*)out)[i] = o;
  }
}

// ---------------- prep: W[K][N] fp32 -> Wt[N][K] bf16 (32x32 LDS transpose)
__global__ __launch_bounds__(256) void transpose_cvt(const float* __restrict__ W,
                                                     u16* __restrict__ Wt,
                                                     int K, int N) {
  __shared__ u16 Ls[32][36];
  const int n0 = blockIdx.x * 32, k0 = blockIdx.y * 32;
  const int t = threadIdx.x;
  {
    int kk = t >> 3, nn4 = (t & 7) * 4;
    float4 v = *(const float4*)(W + (size_t)(k0 + kk) * N + n0 + nn4);
    Ls[kk][nn4 + 0] = f2bf(v.x); Ls[kk][nn4 + 1] = f2bf(v.y);
    Ls[kk][nn4 + 2] = f2bf(v.z); Ls[kk][nn4 + 3] = f2bf(v.w);
  }
  __syncthreads();
  {
    int nn = t >> 3, kk4 = (t & 7) * 4;
    ushort4 o;
    o.x = Ls[kk4 + 0][nn]; o.y = Ls[kk4 + 1][nn];
    o.z = Ls[kk4 + 2][nn]; o.w = Ls[kk4 + 3][nn];
    *(ushort4*)(Wt + (size_t)(n0 + nn) * K + k0 + kk4) = o;
  }
}

// ---------------- bf16 MFMA GEMM core (m97 structure)
#define BKS 32

__device__ __forceinline__ int swz(int row, int c) {
  return row * 4 + (c ^ ((row >> 1) & 3));
}

__device__ __forceinline__ void stage128x32(const u16* __restrict__ G, int ldk,
                                            u16* lds, int w, int lane) {
#pragma unroll
  for (int i = 0; i < 2; ++i) {
    int s = i * 256 + w * 64 + lane;
    int row = s >> 2, c = s & 3;
    int csrc = c ^ ((row >> 1) & 3);
    const u16* src = G + (size_t)row * ldk + csrc * 8;
    u16* dst = lds + (size_t)(i * 256 + w * 64) * 8;
    __builtin_amdgcn_global_load_lds(
        (const __attribute__((address_space(1))) void*)src,
        (__attribute__((address_space(3))) void*)dst, 16, 0, 0);
  }
}

#define GEMM_MAIN_LOOP(Aptr, Bptr, Kdim)                                        \
  __shared__ u16 sm[2][2][128 * BKS];                                           \
  const int tid = threadIdx.x, lane = tid & 63, w = tid >> 6;                   \
  const int wr = w >> 1, wc = w & 1, lrow = lane & 15, lhi = lane >> 4;         \
  const int bm = blockIdx.y * 128, bn = blockIdx.x * 128;                       \
  f32x4 acc[4][4];                                                              \
  _Pragma("unroll") for (int i = 0; i < 4; ++i)                                 \
      _Pragma("unroll") for (int j = 0; j < 4; ++j)                             \
          acc[i][j] = (f32x4){0.f, 0.f, 0.f, 0.f};                              \
  stage128x32(Aptr + (size_t)bm * Kdim, Kdim, sm[0][0], w, lane);               \
  stage128x32(Bptr + (size_t)bn * Kdim, Kdim, sm[0][1], w, lane);               \
  __syncthreads();                                                              \
  const int NT = Kdim / BKS;                                                    \
  for (int t = 0; t < NT; ++t) {                                                \
    int cur = t & 1, nxt = cur ^ 1;                                             \
    if (t + 1 < NT) {                                                           \
      stage128x32(Aptr + (size_t)bm * Kdim + (t + 1) * BKS, Kdim, sm[nxt][0],   \
                  w, lane);                                                     \
      stage128x32(Bptr + (size_t)bn * Kdim + (t + 1) * BKS, Kdim, sm[nxt][1],   \
                  w, lane);                                                     \
    }                                                                           \
    const u16* As = sm[cur][0];                                                 \
    const u16* Bs = sm[cur][1];                                                 \
    bf16x8 af[4], bfr[4];                                                       \
    _Pragma("unroll") for (int mi = 0; mi < 4; ++mi) {                          \
      int row = wr * 64 + mi * 16 + lrow;                                       \
      af[mi] = *(const bf16x8*)(As + (size_t)swz(row, lhi) * 8);                \
    }                                                                           \
    _Pragma("unroll") for (int nj = 0; nj < 4; ++nj) {                          \
      int row = wc * 64 + nj * 16 + lrow;                                       \
      bfr[nj] = *(const bf16x8*)(Bs + (size_t)swz(row, lhi) * 8);               \
    }                                                                           \
    _Pragma("unroll") for (int mi = 0; mi < 4; ++mi)                            \
        _Pragma("unroll") for (int nj = 0; nj < 4; ++nj)                        \
            acc[mi][nj] = __builtin_amdgcn_mfma_f32_16x16x32_bf16(              \
                af[mi], bfr[nj], acc[mi][nj], 0, 0, 0);                         \
    __syncthreads();                                                            \
  }

// QKV GEMM epilogue -> Qb (scaled by 0.125*log2e), Kb, Vt
__global__ __launch_bounds__(256) void gemm_qkv_bf16(
    const u16* __restrict__ Ab, const u16* __restrict__ Btr,
    const float* __restrict__ bias,
    u16* __restrict__ Qb, u16* __restrict__ Kb, u16* __restrict__ Vt) {
  GEMM_MAIN_LOOP(Ab, Btr, N_EMBD)
  const int sector = bn >> 10;
  const float QSC = 0.125f * 1.44269504f;   // fold log2(e) for exp2 softmax
#pragma unroll
  for (int nj = 0; nj < 4; ++nj) {
    int n = bn + wc * 64 + nj * 16 + lrow;
    int h = (n & 1023) >> 6, d = n & 63;
    float bv = bias[n];
#pragma unroll
    for (int mi = 0; mi < 4; ++mi) {
      int mbase = bm + wr * 64 + mi * 16 + lhi * 4;
      int bb_ = mbase >> 11, tt = mbase & 2047;
      if (sector == 0) {
#pragma unroll
        for (int r = 0; r < 4; ++r)
          Qb[((size_t)(bb_ * 16 + h) * TSEQ + tt + r) * HS + d] =
              f2bf((acc[mi][nj][r] + bv) * QSC);
      } else if (sector == 1) {
#pragma unroll
        for (int r = 0; r < 4; ++r)
          Kb[((size_t)(bb_ * 16 + h) * TSEQ + tt + r) * HS + d] =
              f2bf(acc[mi][nj][r] + bv);
      } else {
        ushort4 o;
        o.x = f2bf(acc[mi][nj][0] + bv); o.y = f2bf(acc[mi][nj][1] + bv);
        o.z = f2bf(acc[mi][nj][2] + bv); o.w = f2bf(acc[mi][nj][3] + bv);
        *(ushort4*)(Vt + ((size_t)(bb_ * 16 + h) * HS + d) * TSEQ + tt) = o;
      }
    }
  }
}

// Proj GEMM epilogue -> fp32 out + bias
__global__ __launch_bounds__(256) void gemm_proj_bf16(
    const u16* __restrict__ Ab, const u16* __restrict__ Btr,
    const float* __restrict__ bias, float* __restrict__ C) {
  GEMM_MAIN_LOOP(Ab, Btr, N_EMBD)
#pragma unroll
  for (int nj = 0; nj < 4; ++nj) {
    int n = bn + wc * 64 + nj * 16 + lrow;
    float bv = bias[n];
#pragma unroll
    for (int mi = 0; mi < 4; ++mi) {
      int mbase = bm + wr * 64 + mi * 16 + lhi * 4;
#pragma unroll
      for (int r = 0; r < 4; ++r)
        C[(size_t)(mbase + r) * N_EMBD + n] = acc[mi][nj][r] + bv;
    }
  }
}

// ---------------- MFMA flash attention v2
// 1 wave per block. Wave handles q-tile pair (p, 127-p) of 16 rows each ->
// uniform 33 k-steps. XCD-aware bh decode (4 bh per XCD -> 2MB L2 set).
// K double-buffered in regs (prefetch next step); V issued at step top.
struct Kfrag { bf16x8 r[8]; };

__device__ __forceinline__ void loadK(const u16* __restrict__ Kh, int kb,
                                      int lrow, int lhi, Kfrag& kf) {
#pragma unroll
  for (int s = 0; s < 4; ++s) {
    const u16* base = Kh + (size_t)(kb + 16 * s + lrow) * HS + lhi * 8;
    kf.r[2 * s]     = *(const bf16x8*)(base);
    kf.r[2 * s + 1] = *(const bf16x8*)(base + 32);
  }
}

__global__ __launch_bounds__(64, 2) void attn_mfma(
    const u16* __restrict__ Qb, const u16* __restrict__ Kb,
    const u16* __restrict__ Vt, u16* __restrict__ Y) {
  __shared__ u16 Plds[16][72];

  const int lane = threadIdx.x;
  const int lrow = lane & 15;
  const int lhi  = lane >> 4;

  // XCD-aware decode: xcd = wg & 7 (round-robin heuristic); 4 bh per XCD.
  const int wg  = blockIdx.x;
  const int lin = wg >> 3;                   // 0..255
  const int bh  = ((wg & 7) << 2) | (lin >> 6);
  const int pr  = lin & 63;                  // pair index 0..63
  const int b   = bh >> 4, h = bh & 15;

  const u16* Qh = Qb + (size_t)bh * TSEQ * HS;
  const u16* Kh = Kb + (size_t)bh * TSEQ * HS;
  const u16* Vh = Vt + (size_t)bh * HS * TSEQ;

#pragma unroll
  for (int ti = 0; ti < 2; ++ti) {
    const int itile = (ti == 0) ? pr : (127 - pr);
    const int q0w = itile * 16;
    const int kend = (q0w / 64 + 1) * 64;    // keys rounded up to 64

    bf16x8 aq0 = *(const bf16x8*)(Qh + (size_t)(q0w + lrow) * HS + lhi * 8);
    bf16x8 aq1 = *(const bf16x8*)(Qh + (size_t)(q0w + lrow) * HS + 32 + lhi * 8);

    f32x4 o[4];
    float m_[4], l_[4];
#pragma unroll
    for (int r = 0; r < 4; ++r) { m_[r] = -INFINITY; l_[r] = 0.f; }
#pragma unroll
    for (int ds = 0; ds < 4; ++ds) o[ds] = (f32x4){0.f, 0.f, 0.f, 0.f};

    Kfrag kA, kB;
    loadK(Kh, 0, lrow, lhi, kA);
    int kb = 0;

#define ATTN_STEP(KC, KN)                                                      \
    {                                                                          \
      /* V for this step: issue first (hides under QK + softmax) */           \
      bf16x8 vf[8];                                                            \
      _Pragma("unroll") for (int ks = 0; ks < 2; ++ks)                         \
        _Pragma("unroll") for (int ds = 0; ds < 4; ++ds)                       \
          vf[ks * 4 + ds] = *(const bf16x8*)(                                  \
              Vh + (size_t)(ds * 16 + lrow) * TSEQ + kb + ks * 32 + lhi * 8);  \
      /* prefetch next K into the other register set */                       \
      if (kb + 64 < kend) loadK(Kh, kb + 64, lrow, lhi, KN);                   \
      f32x4 sacc[4];                                                           \
      _Pragma("unroll") for (int s = 0; s < 4; ++s) {                          \
        f32x4 z = (f32x4){0.f, 0.f, 0.f, 0.f};                                 \
        z = __builtin_amdgcn_mfma_f32_16x16x32_bf16(aq0, KC.r[2 * s], z, 0, 0, 0); \
        z = __builtin_amdgcn_mfma_f32_16x16x32_bf16(aq1, KC.r[2 * s + 1], z, 0, 0, 0); \
        sacc[s] = z;                                                           \
      }                                                                        \
      const bool last = (kb + 64 >= kend);                                     \
      if (last) {                                                              \
        _Pragma("unroll") for (int s = 0; s < 4; ++s) {                        \
          int kg = kb + 16 * s + lrow;                                         \
          _Pragma("unroll") for (int r = 0; r < 4; ++r) {                      \
            int qg = q0w + lhi * 4 + r;                                        \
            if (kg > qg) sacc[s][r] = -3.0e38f;                                \
          }                                                                    \
        }                                                                      \
      }                                                                        \
      float corr[4];                                                           \
      _Pragma("unroll") for (int r = 0; r < 4; ++r) {                          \
        float mx = fmaxf(fmaxf(sacc[0][r], sacc[1][r]),                        \
                         fmaxf(sacc[2][r], sacc[3][r]));                       \
        _Pragma("unroll") for (int off = 1; off <= 8; off <<= 1)               \
            mx = fmaxf(mx, __shfl_xor(mx, off));                               \
        float mnew = fmaxf(m_[r], mx);                                         \
        float cr = exp2f(m_[r] - mnew);                                        \
        float ps = 0.f;                                                        \
        _Pragma("unroll") for (int s = 0; s < 4; ++s) {                        \
          float p = exp2f(sacc[s][r] - mnew);                                  \
          ps += p;                                                             \
          Plds[lhi * 4 + r][s * 16 + lrow] = f2bf(p);                          \
        }                                                                      \
        _Pragma("unroll") for (int off = 1; off <= 8; off <<= 1)               \
            ps += __shfl_xor(ps, off);                                         \
        l_[r] = l_[r] * cr + ps;                                               \
        m_[r] = mnew;                                                          \
        corr[r] = cr;                                                          \
      }                                                                        \
      _Pragma("unroll") for (int ds = 0; ds < 4; ++ds)                         \
        _Pragma("unroll") for (int r = 0; r < 4; ++r) o[ds][r] *= corr[r];     \
      _Pragma("unroll") for (int ks = 0; ks < 2; ++ks) {                       \
        bf16x8 pa = *(const bf16x8*)&Plds[lrow][ks * 32 + lhi * 8];            \
        _Pragma("unroll") for (int ds = 0; ds < 4; ++ds)                       \
          o[ds] = __builtin_amdgcn_mfma_f32_16x16x32_bf16(                     \
              pa, vf[ks * 4 + ds], o[ds], 0, 0, 0);                            \
      }                                                                        \
      kb += 64;                                                                \
    }

    while (true) {
      ATTN_STEP(kA, kB)
      if (kb >= kend) break;
      ATTN_STEP(kB, kA)
      if (kb >= kend) break;
    }
#undef ATTN_STEP

    // epilogue
#pragma unroll
    for (int r = 0; r < 4; ++r) {
      float inv = 1.0f / l_[r];
      int q = q0w + lhi * 4 + r;
#pragma unroll
      for (int ds = 0; ds < 4; ++ds)
        Y[((size_t)(b * TSEQ + q)) * N_EMBD + h * HS + ds * 16 + lrow] =
            f2bf(o[ds][r] * inv);
    }
  }
}

extern "C" void kernel_launch(void* const* d_in, const int* in_sizes, int n_in,
                              void* d_out, int out_size, void* d_ws, size_t ws_size,
                              hipStream_t stream) {
  const float* x      = (const float*)d_in[0];
  const float* W_attn = (const float*)d_in[1];
  const float* b_attn = (const float*)d_in[2];
  const float* W_proj = (const float*)d_in[3];
  const float* b_proj = (const float*)d_in[4];
  float* out = (float*)d_out;

  u16* xb  = (u16*)d_ws;
  u16* Wat = xb  + (size_t)BT * N_EMBD;
  u16* Wpt = Wat + (size_t)3 * N_EMBD * N_EMBD;
  u16* Qb  = Wpt + (size_t)N_EMBD * N_EMBD;
  u16* Kb  = Qb  + (size_t)BT * N_EMBD;
  u16* Vt  = Kb  + (size_t)BT * N_EMBD;
  u16* yb  = Vt  + (size_t)BT * N_EMBD;

  cvt_bf16<<<(BT * N_EMBD / 4 + 255) / 256, 256, 0, stream>>>(x, xb, BT * N_EMBD / 4);
  {
    dim3 g1(3 * N_EMBD / 32, N_EMBD / 32);
    transpose_cvt<<<g1, 256, 0, stream>>>(W_attn, Wat, N_EMBD, 3 * N_EMBD);
    dim3 g2(N_EMBD / 32, N_EMBD / 32);
    transpose_cvt<<<g2, 256, 0, stream>>>(W_proj, Wpt, N_EMBD, N_EMBD);
  }
  {
    dim3 grid(3 * N_EMBD / 128, BT / 128);
    gemm_qkv_bf16<<<grid, 256, 0, stream>>>(xb, Wat, b_attn, Qb, Kb, Vt);
  }
  {
    attn_mfma<<<2048, 64, 0, stream>>>(Qb, Kb, Vt, yb);
  }
  {
    dim3 grid(N_EMBD / 128, BT / 128);
    gemm_proj_bf16<<<grid, 256, 0, stream>>>(yb, Wpt, b_proj, out);
  }
}